// Round 6
// baseline (1107.515 us; speedup 1.0000x reference)
//
#include <hip/hip_runtime.h>

#define B_ 64
#define T_ 2048
#define IN_ 64
#define H_ 128
#define C_ 8

typedef _Float16 f16x2 __attribute__((ext_vector_type(2)));

// RTZ packed convert — weights only (one-time, bias harmless)
__device__ __forceinline__ f16x2 pkw(float a, float b) {
  return __builtin_bit_cast(f16x2, __builtin_amdgcn_cvt_pkrtz(a, b));
}
// RNE converts — recurrent state / xp (matches round-2 accuracy)
__device__ __forceinline__ f16x2 pk_rne(float a, float b) {
  f16x2 r; r.x = (_Float16)a; r.y = (_Float16)b; return r;
}
__device__ __forceinline__ f16x2 as_h2(int v) { return __builtin_bit_cast(f16x2, v); }

__device__ __forceinline__ float dot2(f16x2 a, f16x2 b, float c) {
#if __has_builtin(__builtin_amdgcn_fdot2)
  return __builtin_amdgcn_fdot2(a, b, c, false);
#else
  float r;
  asm("v_dot2_f32_f16 %0, %1, %2, %3" : "=v"(r) : "v"(a), "v"(b), "v"(c));
  return r;
#endif
}

__device__ __forceinline__ float tanh_fast(float x) {
  // tanh(x) = 1 - 2/(exp2(x*2*log2e)+1); saturates correctly at +-inf
  float e = __builtin_amdgcn_exp2f(x * 2.8853900817779268f);
  return 1.0f - 2.0f * __builtin_amdgcn_rcpf(e + 1.0f);
}

template <int CTRL>
__device__ __forceinline__ float dpp_add(float v) {   // v + dpp_perm(v), VALU only
  return v + __int_as_float(__builtin_amdgcn_update_dpp(
                 0, __float_as_int(v), CTRL, 0xF, 0xF, true));
}
// sum over 4-lane groups (lane&3): quad_perm xor1 + xor2
__device__ __forceinline__ float red4(float v) {
  return dpp_add<0x4E>(dpp_add<0xB1>(v));
}
// sum over 8-lane groups (lane&7), valid on ALL lanes:
// xor1 + xor2 + ROW_HALF_MIRROR (0x141; lane i <-> 7-i within each 8-half —
// symmetric, so each quad adds the other quad's partial)
__device__ __forceinline__ float red8(float v) {
  return dpp_add<0x141>(dpp_add<0x4E>(dpp_add<0xB1>(v)));
}

// barrier without vmcnt(0) drain (keeps global prefetch loads in flight)
__device__ __forceinline__ void block_sync_lds() {
  asm volatile("s_waitcnt lgkmcnt(0)" ::: "memory");
  __builtin_amdgcn_s_barrier();
  asm volatile("" ::: "memory");
}

#define DOT8(A, Q, W, BASE)            \
  A = dot2(as_h2(Q.x), W[BASE+0], A);  \
  A = dot2(as_h2(Q.y), W[BASE+1], A);  \
  A = dot2(as_h2(Q.z), W[BASE+2], A);  \
  A = dot2(as_h2(Q.w), W[BASE+3], A);

// ---------------- kernel 1: xp0 = f16(x @ W_ih0^T + b_ih0 + b_hh0) ----------------
__global__ __launch_bounds__(256) void k_xproj(
    const float* __restrict__ x, const float* __restrict__ Wih0,
    const float* __restrict__ bih0, const float* __restrict__ bhh0,
    _Float16* __restrict__ xp) {
  __shared__ __align__(16) _Float16 xs[4][2][IN_];
  const int wave = threadIdx.x >> 6, lane = threadIdx.x & 63;
  const int gw = blockIdx.x * 4 + wave;
  const int ROWS = 32;
  const size_t r0 = (size_t)gw * ROWS;

  f16x2 wA[32], wB[32];
  const float2* W2 = (const float2*)Wih0;
#pragma unroll
  for (int p = 0; p < 32; ++p) {
    float2 a = W2[(lane * 2) * 32 + p];
    float2 b = W2[(lane * 2 + 1) * 32 + p];
    wA[p] = pkw(a.x, a.y); wB[p] = pkw(b.x, b.y);
  }
  const float ba = bih0[lane * 2] + bhh0[lane * 2];
  const float bb = bih0[lane * 2 + 1] + bhh0[lane * 2 + 1];

  xs[wave][0][lane] = (_Float16)x[r0 * IN_ + lane];
  float xn = x[(r0 + 1) * IN_ + lane];
  for (int rr = 0; rr < ROWS; ++rr) {
    const int buf = rr & 1;
    if (rr + 1 < ROWS) xs[wave][buf ^ 1][lane] = (_Float16)xn;
    if (rr + 2 < ROWS) xn = x[(r0 + rr + 2) * IN_ + lane];
    asm volatile("s_waitcnt lgkmcnt(0)" ::: "memory");
    const int4* xv = (const int4*)xs[wave][buf];
    int4 q0 = xv[0], q1 = xv[1], q2 = xv[2], q3 = xv[3];
    int4 q4 = xv[4], q5 = xv[5], q6 = xv[6], q7 = xv[7];
    float a0 = 0.f, a1 = 0.f, c0 = 0.f, c1 = 0.f;
    DOT8(a0, q0, wA, 0)  DOT8(c0, q0, wB, 0)
    DOT8(a1, q1, wA, 4)  DOT8(c1, q1, wB, 4)
    DOT8(a0, q2, wA, 8)  DOT8(c0, q2, wB, 8)
    DOT8(a1, q3, wA, 12) DOT8(c1, q3, wB, 12)
    DOT8(a0, q4, wA, 16) DOT8(c0, q4, wB, 16)
    DOT8(a1, q5, wA, 20) DOT8(c1, q5, wB, 20)
    DOT8(a0, q6, wA, 24) DOT8(c0, q6, wB, 24)
    DOT8(a1, q7, wA, 28) DOT8(c1, q7, wB, 28)
    *(f16x2*)&xp[(r0 + rr) * H_ + lane * 2] = pk_rne(a0 + a1 + ba, c0 + c1 + bb);
  }
}

// ---------------- kernel 2: fused recurrence, skewed pipeline ----------------
// LDS: hlds[4][128] f16 = [h1 slot0][h1 slot1][h2 slot0][h2 slot1]
// phase p: L0 computes h1[p]          (reads h1[p-1],  slot (p-1)&1; writes slot p&1)
//          L1 computes h2[p-2] = tanh(ihpart(p-1) + Whh1@h2[p-3] + b)
//                                      (reads h2[p-3], slot (p-1)&1; writes slot p&1)
//             off-path: ihpart for next phase from h1[p-1] (slot (p-1)&1)
//          FC computes logits[p-3]    (reads h2[p-3],  slot (p-1)&1)
// int4 bases: h1s0=0 h1s1=16 h2s0=32 h2s1=48 ; f16x2 bases: 0/64/128/192

#define L0PH(PP, XA, RB, WPB)                                          \
  {                                                                    \
    block_sync_lds();                                                  \
    const int p_ = (PP);                                               \
    if (p_ < T_) {                                                     \
      const float fx = (float)XA.x, fy = (float)XA.y;                  \
      int4 q0 = hp[(RB) + kq4 + 0], q1 = hp[(RB) + kq4 + 1];           \
      int4 q2 = hp[(RB) + kq4 + 2], q3 = hp[(RB) + kq4 + 3];           \
      float a0 = 0.f, a1 = 0.f, c0 = 0.f, c1 = 0.f;                    \
      DOT8(a0, q0, wA, 0)  DOT8(c0, q0, wB, 0)                         \
      DOT8(a1, q1, wA, 4)  DOT8(c1, q1, wB, 4)                         \
      DOT8(a0, q2, wA, 8)  DOT8(c0, q2, wB, 8)                         \
      DOT8(a1, q3, wA, 12) DOT8(c1, q3, wB, 12)                        \
      float t0 = tanh_fast(red4(a0 + a1) + fx);                        \
      float t1 = tanh_fast(red4(c0 + c1) + fy);                        \
      if (kq == 0) {                                                   \
        wp[(WPB) + jx] = pk_rne(t0, t1);                               \
        const int pp = p_ + 4;                                         \
        if (pp < T_) XA = xp2[xpb + (size_t)pp * 64 + jx];             \
      }                                                                \
    }                                                                  \
  }

#define L1PH(PP, RH2, WPB, RH1)                                        \
  {                                                                    \
    block_sync_lds();                                                  \
    const int p_ = (PP);                                               \
    if (p_ >= 2 && p_ < T_ + 2) {                                      \
      int4 h0 = hp[(RH2) + kg2], h1v = hp[(RH2) + kg2 + 1];            \
      float a = pi0, c = pi1;                                          \
      DOT8(a, h0, whA, 0) DOT8(a, h1v, whA, 4)                         \
      DOT8(c, h0, whB, 0) DOT8(c, h1v, whB, 4)                         \
      float t0 = tanh_fast(red8(a) + bA);                              \
      float t1 = tanh_fast(red8(c) + bB);                              \
      if (kg == 0) wp[(WPB) + jy] = pk_rne(t0, t1);                    \
    }                                                                  \
    if (p_ <= T_) {                                                    \
      int4 g0 = hp[(RH1) + kg2], g1 = hp[(RH1) + kg2 + 1];             \
      float x0 = 0.f, x1 = 0.f;                                        \
      DOT8(x0, g0, wiA, 0) DOT8(x0, g1, wiA, 4)                        \
      DOT8(x1, g0, wiB, 0) DOT8(x1, g1, wiB, 4)                        \
      pi0 = x0; pi1 = x1;                                              \
    }                                                                  \
  }

#define FCPH(PP, RB)                                                   \
  {                                                                    \
    block_sync_lds();                                                  \
    const int p_ = (PP);                                               \
    if (p_ >= 3 && p_ < T_ + 3) {                                      \
      int4 h0 = hp[(RB) + kg2], h1v = hp[(RB) + kg2 + 1];              \
      float a = 0.f;                                                   \
      DOT8(a, h0, wf, 0) DOT8(a, h1v, wf, 4)                           \
      float r = red8(a);                                               \
      if (k8 == 0) outb[(size_t)(p_ - 3) * C_ + cc] = r + bv;          \
    }                                                                  \
  }

__global__ __launch_bounds__(832) void k_rnn(
    const _Float16* __restrict__ xp0,
    const float* __restrict__ Whh0,
    const float* __restrict__ Wih1,
    const float* __restrict__ Whh1,
    const float* __restrict__ bih1,
    const float* __restrict__ bhh1,
    const float* __restrict__ Wfc,
    const float* __restrict__ bfc,
    float* __restrict__ out) {
  __shared__ __align__(16) _Float16 hlds[4][H_];

  const int tid  = threadIdx.x;
  const int wave = tid >> 6;
  const int lane = tid & 63;
  const int b    = blockIdx.x;

  if (tid < 256) ((int*)hlds)[tid] = 0;     // zero all ring slots (h0 = 0)
  const int4* hp = (const int4*)hlds;
  f16x2*      wp = (f16x2*)hlds;
  block_sync_lds();

  if (wave < 4) {
    // -------- layer 0: 4 waves; lane = (jj 0..15, kq 0..3); outputs j0, j0+1
    const int jj = lane >> 2, kq = lane & 3;
    const int kq4 = kq * 4;
    const int j0 = wave * 32 + jj * 2;
    const int jx = wave * 16 + jj;          // f16x2 index of output pair
    f16x2 wA[16], wB[16];
    const float2* W2 = (const float2*)Whh0;  // row stride 64 float2
#pragma unroll
    for (int m = 0; m < 4; ++m)
#pragma unroll
      for (int e = 0; e < 4; ++e) {
        float2 a = W2[j0 * 64 + kq * 16 + m * 4 + e];
        float2 bt = W2[(j0 + 1) * 64 + kq * 16 + m * 4 + e];
        wA[m * 4 + e] = pkw(a.x, a.y);
        wB[m * 4 + e] = pkw(bt.x, bt.y);
      }
    const size_t xpb = (size_t)b * T_ * 64;  // f16x2 units
    const f16x2* xp2 = (const f16x2*)xp0;
    f16x2 XA0 = {0,0}, XA1 = {0,0}, XA2 = {0,0}, XA3 = {0,0};
    if (kq == 0) {
      XA0 = xp2[xpb + 0 * 64 + jx]; XA1 = xp2[xpb + 1 * 64 + jx];
      XA2 = xp2[xpb + 2 * 64 + jx]; XA3 = xp2[xpb + 3 * 64 + jx];
    }
    for (int p0 = 0; p0 < T_ + 4; p0 += 4) {   // 2052 phases
      L0PH(p0 + 0, XA0, 16, 0)     // even: read h1 slot1, write slot0
      L0PH(p0 + 1, XA1, 0, 64)     // odd : read slot0, write slot1
      L0PH(p0 + 2, XA2, 16, 0)
      L0PH(p0 + 3, XA3, 0, 64)
    }
  } else if (wave < 12) {
    // -------- layer 1: 8 waves; lane = (jj 0..7, kg 0..7); outputs j0, j0+1
    const int u = wave - 4;
    const int jj = lane >> 3, kg = lane & 7;
    const int kg2 = kg * 2;
    const int j0 = u * 16 + jj * 2;
    const int jy = u * 8 + jj;               // f16x2 index within h2 slot
    f16x2 whA[8], whB[8], wiA[8], wiB[8];
    const float2* Wh2 = (const float2*)Whh1;
    const float2* Wi2 = (const float2*)Wih1;
#pragma unroll
    for (int n = 0; n < 8; ++n) {
      float2 a = Wi2[j0 * 64 + kg * 8 + n];        wiA[n] = pkw(a.x, a.y);
      float2 bq = Wi2[(j0 + 1) * 64 + kg * 8 + n]; wiB[n] = pkw(bq.x, bq.y);
      float2 cq = Wh2[j0 * 64 + kg * 8 + n];       whA[n] = pkw(cq.x, cq.y);
      float2 dq = Wh2[(j0 + 1) * 64 + kg * 8 + n]; whB[n] = pkw(dq.x, dq.y);
    }
    const float bA = bih1[j0] + bhh1[j0];
    const float bB = bih1[j0 + 1] + bhh1[j0 + 1];
    float pi0 = 0.f, pi1 = 0.f;              // ih partials (computed phase-early)
    for (int p0 = 0; p0 < T_ + 4; p0 += 2) {
      L1PH(p0 + 0, 48, 128, 16)    // even: rd h2 slot1, wr slot0, rd h1 slot1
      L1PH(p0 + 1, 32, 192, 0)     // odd : rd h2 slot0, wr slot1, rd h1 slot0
    }
  } else {
    // -------- FC head: 1 wave; lane = (cc 0..7, k8 0..7)
    const int cc = lane >> 3, k8 = lane & 7;
    const int kg2 = k8 * 2;
    f16x2 wf[8];
    const float2* W2 = (const float2*)Wfc;
#pragma unroll
    for (int n = 0; n < 8; ++n) {
      float2 a = W2[cc * 64 + k8 * 8 + n];
      wf[n] = pkw(a.x, a.y);
    }
    const float bv = bfc[cc];
    float* outb = out + (size_t)b * T_ * C_;
    for (int p0 = 0; p0 < T_ + 4; p0 += 2) {
      FCPH(p0 + 0, 48)             // even: read h2 slot1
      FCPH(p0 + 1, 32)             // odd : read h2 slot0
    }
  }
}

// ---------------- launch ----------------
extern "C" void kernel_launch(void* const* d_in, const int* in_sizes, int n_in,
                              void* d_out, int out_size, void* d_ws, size_t ws_size,
                              hipStream_t stream) {
  const float* x    = (const float*)d_in[0];
  const float* Wih0 = (const float*)d_in[1];
  const float* Whh0 = (const float*)d_in[2];
  const float* bih0 = (const float*)d_in[3];
  const float* bhh0 = (const float*)d_in[4];
  const float* Wih1 = (const float*)d_in[5];
  const float* Whh1 = (const float*)d_in[6];
  const float* bih1 = (const float*)d_in[7];
  const float* bhh1 = (const float*)d_in[8];
  const float* Wfc  = (const float*)d_in[9];
  const float* bfc  = (const float*)d_in[10];
  float* outp = (float*)d_out;
  _Float16* xp0 = (_Float16*)d_ws;           // B*T*H f16 = 32 MiB scratch

  k_xproj<<<1024, 256, 0, stream>>>(x, Wih0, bih0, bhh0, xp0);
  k_rnn<<<64, 832, 0, stream>>>(xp0, Whh0, Wih1, Whh1, bih1, bhh1, Wfc, bfc, outp);
}

// Round 7
// 1011.833 us; speedup vs baseline: 1.0946x; 1.0946x over previous
//
#include <hip/hip_runtime.h>

#define B_ 64
#define T_ 2048
#define IN_ 64
#define H_ 128
#define C_ 8

typedef _Float16 f16x2 __attribute__((ext_vector_type(2)));

// RTZ packed convert - weights only (one-time)
__device__ __forceinline__ f16x2 pkw(float a, float b) {
  return __builtin_bit_cast(f16x2, __builtin_amdgcn_cvt_pkrtz(a, b));
}
// RNE converts - recurrent state / xp
__device__ __forceinline__ f16x2 pk_rne(float a, float b) {
  f16x2 r; r.x = (_Float16)a; r.y = (_Float16)b; return r;
}
__device__ __forceinline__ f16x2 as_h2(int v) { return __builtin_bit_cast(f16x2, v); }

__device__ __forceinline__ float dot2(f16x2 a, f16x2 b, float c) {
#if __has_builtin(__builtin_amdgcn_fdot2)
  return __builtin_amdgcn_fdot2(a, b, c, false);
#else
  float r;
  asm("v_dot2_f32_f16 %0, %1, %2, %3" : "=v"(r) : "v"(a), "v"(b), "v"(c));
  return r;
#endif
}

__device__ __forceinline__ float tanh_fast(float x) {
  float e = __builtin_amdgcn_exp2f(x * 2.8853900817779268f);
  return 1.0f - 2.0f * __builtin_amdgcn_rcpf(e + 1.0f);
}

template <int CTRL>
__device__ __forceinline__ float dpp_add(float v) {
  return v + __int_as_float(__builtin_amdgcn_update_dpp(
                 0, __float_as_int(v), CTRL, 0xF, 0xF, true));
}
// sum over 4-lane groups: quad_perm xor1 + xor2
__device__ __forceinline__ float red4(float v) {
  return dpp_add<0x4E>(dpp_add<0xB1>(v));
}
// sum over 8-lane groups on all lanes: xor1 + xor2 + ROW_HALF_MIRROR
__device__ __forceinline__ float red8(float v) {
  return dpp_add<0x141>(dpp_add<0x4E>(dpp_add<0xB1>(v)));
}

// barrier without vmcnt(0) drain
__device__ __forceinline__ void block_sync_lds() {
  asm volatile("s_waitcnt lgkmcnt(0)" ::: "memory");
  __builtin_amdgcn_s_barrier();
  asm volatile("" ::: "memory");
}

#define DOT8(A, Q, W, BASE)            \
  A = dot2(as_h2(Q.x), W[BASE+0], A);  \
  A = dot2(as_h2(Q.y), W[BASE+1], A);  \
  A = dot2(as_h2(Q.z), W[BASE+2], A);  \
  A = dot2(as_h2(Q.w), W[BASE+3], A);

// ---------------- kernel 1: xp0 = f16(x @ W_ih0^T + b_ih0 + b_hh0) ----------------
__global__ __launch_bounds__(256) void k_xproj(
    const float* __restrict__ x, const float* __restrict__ Wih0,
    const float* __restrict__ bih0, const float* __restrict__ bhh0,
    _Float16* __restrict__ xp) {
  __shared__ __align__(16) _Float16 xs[4][2][IN_];
  const int wave = threadIdx.x >> 6, lane = threadIdx.x & 63;
  const int gw = blockIdx.x * 4 + wave;          // 0..8191
  const int ROWS = 16;                           // 8192 waves * 16 = 131072 rows
  const size_t r0 = (size_t)gw * ROWS;

  f16x2 wA[32], wB[32];
  const float2* W2 = (const float2*)Wih0;
#pragma unroll
  for (int p = 0; p < 32; ++p) {
    float2 a = W2[(lane * 2) * 32 + p];
    float2 b = W2[(lane * 2 + 1) * 32 + p];
    wA[p] = pkw(a.x, a.y); wB[p] = pkw(b.x, b.y);
  }
  const float ba = bih0[lane * 2] + bhh0[lane * 2];
  const float bb = bih0[lane * 2 + 1] + bhh0[lane * 2 + 1];

  xs[wave][0][lane] = (_Float16)x[r0 * IN_ + lane];
  float xn = x[(r0 + 1) * IN_ + lane];
  for (int rr = 0; rr < ROWS; ++rr) {
    const int buf = rr & 1;
    if (rr + 1 < ROWS) xs[wave][buf ^ 1][lane] = (_Float16)xn;
    if (rr + 2 < ROWS) xn = x[(r0 + rr + 2) * IN_ + lane];
    asm volatile("s_waitcnt lgkmcnt(0)" ::: "memory");
    const int4* xv = (const int4*)xs[wave][buf];
    int4 q0 = xv[0], q1 = xv[1], q2 = xv[2], q3 = xv[3];
    int4 q4 = xv[4], q5 = xv[5], q6 = xv[6], q7 = xv[7];
    float a0 = 0.f, a1 = 0.f, c0 = 0.f, c1 = 0.f;
    DOT8(a0, q0, wA, 0)  DOT8(c0, q0, wB, 0)
    DOT8(a1, q1, wA, 4)  DOT8(c1, q1, wB, 4)
    DOT8(a0, q2, wA, 8)  DOT8(c0, q2, wB, 8)
    DOT8(a1, q3, wA, 12) DOT8(c1, q3, wB, 12)
    DOT8(a0, q4, wA, 16) DOT8(c0, q4, wB, 16)
    DOT8(a1, q5, wA, 20) DOT8(c1, q5, wB, 20)
    DOT8(a0, q6, wA, 24) DOT8(c0, q6, wB, 24)
    DOT8(a1, q7, wA, 28) DOT8(c1, q7, wB, 28)
    *(f16x2*)&xp[(r0 + rr) * H_ + lane * 2] = pk_rne(a0 + a1 + ba, c0 + c1 + bb);
  }
}

// ---------------- kernel 2: fused recurrence, skewed pipeline ----------------
// LDS: hlds[4][128] f16 = [h1 slot0][h1 slot1][h2 slot0][h2 slot1]
// phase p: L0: h1[p] = tanh(xp[p] + Whh0@h1[p-1])          rd slot (p-1)&1, wr p&1
//          L1: h2[p-2] = tanh(ihp(p-2) + Whh1@h2[p-3] + b) rd slot (p-1)&1, wr p&1
//              off-chain: ihp(p-1) partials from h1[p-1]
//          FC (on L1 wave 4): logits[p-3] from h2[p-3]     rd slot (p-1)&1
// int4 slot bases: h1s0=0 h1s1=16 h2s0=32 h2s1=48 ; f16x2 bases: 0/64/128/192
// Guards exist only in prologue (p 0..3) and epilogue (p 2040..2051); main loop
// (p 4..2039) is branch-free.

#define L0PH(PP, XA, RB, WPB, G)                                       \
  {                                                                    \
    block_sync_lds();                                                  \
    const int p_ = (PP);                                               \
    if (!(G) || (p_ < T_)) {                                           \
      const float fx = (float)XA.x, fy = (float)XA.y;                  \
      int4 q0 = hp[(RB) + kq4 + 0], q1 = hp[(RB) + kq4 + 1];           \
      int4 q2 = hp[(RB) + kq4 + 2], q3 = hp[(RB) + kq4 + 3];           \
      float a0 = 0.f, a1 = 0.f, c0 = 0.f, c1 = 0.f;                    \
      DOT8(a0, q0, wA, 0)  DOT8(c0, q0, wB, 0)                         \
      DOT8(a1, q1, wA, 4)  DOT8(c1, q1, wB, 4)                         \
      DOT8(a0, q2, wA, 8)  DOT8(c0, q2, wB, 8)                         \
      DOT8(a1, q3, wA, 12) DOT8(c1, q3, wB, 12)                        \
      float t0 = tanh_fast(red4(a0 + a1) + fx);                        \
      float t1 = tanh_fast(red4(c0 + c1) + fy);                        \
      if (kq == 0) wp[(WPB) + jx] = pk_rne(t0, t1);                    \
    }                                                                  \
    if (!(G) || (p_ + 4 < T_)) {                                       \
      XA = xp2[xpb + (size_t)(p_ + 4) * 64 + jx];                      \
    }                                                                  \
  }

#define L1PH(PP, RH2, WPB, RH1, G)                                     \
  {                                                                    \
    block_sync_lds();                                                  \
    const int p_ = (PP);                                               \
    if (!(G) || (p_ >= 2 && p_ < T_ + 2)) {                            \
      int4 h0 = hp[(RH2) + kg2], h1v = hp[(RH2) + kg2 + 1];            \
      float a = pi0, c = pi1;                                          \
      DOT8(a, h0, whA, 0) DOT8(a, h1v, whA, 4)                         \
      DOT8(c, h0, whB, 0) DOT8(c, h1v, whB, 4)                         \
      float t0 = tanh_fast(red8(a) + bA);                              \
      float t1 = tanh_fast(red8(c) + bB);                              \
      if (kg == 0) wp[(WPB) + jy] = pk_rne(t0, t1);                    \
    }                                                                  \
    if (fcw && (!(G) || (p_ >= 3 && p_ < T_ + 3))) {                   \
      int4 f0 = hp[(RH2) + kg2], f1 = hp[(RH2) + kg2 + 1];             \
      float fa = 0.f;                                                  \
      DOT8(fa, f0, wf, 0) DOT8(fa, f1, wf, 4)                          \
      float fr = red8(fa);                                             \
      if (kg == 0) outb[(size_t)(p_ - 3) * C_ + jj] = fr + bv;         \
    }                                                                  \
    if (!(G) || (p_ <= T_)) {                                          \
      int4 g0 = hp[(RH1) + kg2], g1 = hp[(RH1) + kg2 + 1];             \
      float x0 = 0.f, x1 = 0.f;                                        \
      DOT8(x0, g0, wiA, 0) DOT8(x0, g1, wiA, 4)                        \
      DOT8(x1, g0, wiB, 0) DOT8(x1, g1, wiB, 4)                        \
      pi0 = x0; pi1 = x1;                                              \
    }                                                                  \
  }

__global__ __launch_bounds__(768) void k_rnn(
    const _Float16* __restrict__ xp0,
    const float* __restrict__ Whh0,
    const float* __restrict__ Wih1,
    const float* __restrict__ Whh1,
    const float* __restrict__ bih1,
    const float* __restrict__ bhh1,
    const float* __restrict__ Wfc,
    const float* __restrict__ bfc,
    float* __restrict__ out) {
  __shared__ __align__(16) _Float16 hlds[4][H_];

  const int tid  = threadIdx.x;
  const int wave = tid >> 6;
  const int lane = tid & 63;
  const int b    = blockIdx.x;

  if (tid < 256) ((int*)hlds)[tid] = 0;     // zero all ring slots (h0 = 0)
  const int4* hp = (const int4*)hlds;
  f16x2*      wp = (f16x2*)hlds;
  block_sync_lds();

  if (wave < 4) {
    // -------- layer 0: 4 waves; lane = (jj 0..15, kq 0..3); outputs j0, j0+1
    const int jj = lane >> 2, kq = lane & 3;
    const int kq4 = kq * 4;
    const int j0 = wave * 32 + jj * 2;
    const int jx = wave * 16 + jj;
    f16x2 wA[16], wB[16];
    const float2* W2 = (const float2*)Whh0;
#pragma unroll
    for (int m = 0; m < 4; ++m)
#pragma unroll
      for (int e = 0; e < 4; ++e) {
        float2 a = W2[j0 * 64 + kq * 16 + m * 4 + e];
        float2 bt = W2[(j0 + 1) * 64 + kq * 16 + m * 4 + e];
        wA[m * 4 + e] = pkw(a.x, a.y);
        wB[m * 4 + e] = pkw(bt.x, bt.y);
      }
    const size_t xpb = (size_t)b * T_ * 64;
    const f16x2* xp2 = (const f16x2*)xp0;
    f16x2 XA0 = xp2[xpb + 0 * 64 + jx], XA1 = xp2[xpb + 1 * 64 + jx];
    f16x2 XA2 = xp2[xpb + 2 * 64 + jx], XA3 = xp2[xpb + 3 * 64 + jx];
    __builtin_amdgcn_s_setprio(1);          // h1 chain paces the block
    // prologue p = 0..3
    L0PH(0, XA0, 16, 0, 1) L0PH(1, XA1, 0, 64, 1)
    L0PH(2, XA2, 16, 0, 1) L0PH(3, XA3, 0, 64, 1)
    // main p = 4..2039, branch-free
    for (int p0 = 4; p0 < 2040; p0 += 4) {
      L0PH(p0 + 0, XA0, 16, 0, 0)
      L0PH(p0 + 1, XA1, 0, 64, 0)
      L0PH(p0 + 2, XA2, 16, 0, 0)
      L0PH(p0 + 3, XA3, 0, 64, 0)
    }
    // epilogue p = 2040..2051
    for (int p0 = 2040; p0 < 2052; p0 += 4) {
      L0PH(p0 + 0, XA0, 16, 0, 1)
      L0PH(p0 + 1, XA1, 0, 64, 1)
      L0PH(p0 + 2, XA2, 16, 0, 1)
      L0PH(p0 + 3, XA3, 0, 64, 1)
    }
  } else {
    // -------- layer 1: 8 waves; lane = (jj 0..7, kg 0..7); outputs j0, j0+1
    const int u = wave - 4;
    const int jj = lane >> 3, kg = lane & 7;
    const int kg2 = kg * 2;
    const int j0 = u * 16 + jj * 2;
    const int jy = u * 8 + jj;
    const bool fcw = (u == 0);               // wave 4 also does the FC head
    f16x2 whA[8], whB[8], wiA[8], wiB[8], wf[8];
    const float2* Wh2 = (const float2*)Whh1;
    const float2* Wi2 = (const float2*)Wih1;
#pragma unroll
    for (int n = 0; n < 8; ++n) {
      float2 a = Wi2[j0 * 64 + kg * 8 + n];        wiA[n] = pkw(a.x, a.y);
      float2 bq = Wi2[(j0 + 1) * 64 + kg * 8 + n]; wiB[n] = pkw(bq.x, bq.y);
      float2 cq = Wh2[j0 * 64 + kg * 8 + n];       whA[n] = pkw(cq.x, cq.y);
      float2 dq = Wh2[(j0 + 1) * 64 + kg * 8 + n]; whB[n] = pkw(dq.x, dq.y);
    }
    float bv = 0.f;
    if (fcw) {
      const float2* Wf2 = (const float2*)Wfc;
#pragma unroll
      for (int n = 0; n < 8; ++n) {
        float2 a = Wf2[jj * 64 + kg * 8 + n];      // class jj, K-octant kg
        wf[n] = pkw(a.x, a.y);
      }
      bv = bfc[jj];
    }
    const float bA = bih1[j0] + bhh1[j0];
    const float bB = bih1[j0 + 1] + bhh1[j0 + 1];
    float* outb = out + (size_t)b * T_ * C_;
    float pi0 = 0.f, pi1 = 0.f;
    // prologue p = 0..3
    L1PH(0, 48, 128, 16, 1) L1PH(1, 32, 192, 0, 1)
    L1PH(2, 48, 128, 16, 1) L1PH(3, 32, 192, 0, 1)
    // main p = 4..2039, branch-free
    for (int p0 = 4; p0 < 2040; p0 += 2) {
      L1PH(p0 + 0, 48, 128, 16, 0)
      L1PH(p0 + 1, 32, 192, 0, 0)
    }
    // epilogue p = 2040..2051
    for (int p0 = 2040; p0 < 2052; p0 += 2) {
      L1PH(p0 + 0, 48, 128, 16, 1)
      L1PH(p0 + 1, 32, 192, 0, 1)
    }
  }
}

// ---------------- launch ----------------
extern "C" void kernel_launch(void* const* d_in, const int* in_sizes, int n_in,
                              void* d_out, int out_size, void* d_ws, size_t ws_size,
                              hipStream_t stream) {
  const float* x    = (const float*)d_in[0];
  const float* Wih0 = (const float*)d_in[1];
  const float* Whh0 = (const float*)d_in[2];
  const float* bih0 = (const float*)d_in[3];
  const float* bhh0 = (const float*)d_in[4];
  const float* Wih1 = (const float*)d_in[5];
  const float* Whh1 = (const float*)d_in[6];
  const float* bih1 = (const float*)d_in[7];
  const float* bhh1 = (const float*)d_in[8];
  const float* Wfc  = (const float*)d_in[9];
  const float* bfc  = (const float*)d_in[10];
  float* outp = (float*)d_out;
  _Float16* xp0 = (_Float16*)d_ws;           // B*T*H f16 = 32 MiB scratch

  k_xproj<<<2048, 256, 0, stream>>>(x, Wih0, bih0, bhh0, xp0);
  k_rnn<<<64, 768, 0, stream>>>(xp0, Whh0, Wih1, Whh1, bih1, bhh1, Wfc, bfc, outp);
}